// Round 1
// baseline (1580.858 us; speedup 1.0000x reference)
//
#include <hip/hip_runtime.h>
#include <hip/hip_bf16.h>

// ---------------- problem constants ----------------
#define B_  16
#define S_  5
#define W_  12
#define NL_ 49
#define H_  1024
#define V_  15000
#define SEQ_N   14400000          // B*S*W*V
#define STOP_N  80
#define OUT_STOP (SEQ_N)
#define OUT_SCORE (SEQ_N + STOP_N)

typedef __attribute__((ext_vector_type(8))) short     short8;
typedef __attribute__((ext_vector_type(4))) float     f32x4;
typedef __attribute__((ext_vector_type(4))) unsigned int u32x4;
typedef __attribute__((ext_vector_type(4))) unsigned short us4;

// ---------------- ws layout (bytes) ----------------
#define OFF_FCWT   0ull            // 15000x1024 bf16  30,720,000
#define OFF_WWHH   30720000ull     // 4096x1024 bf16
#define OFF_WWIH   39108608ull     // 4096x1024 bf16
#define OFF_WSCAT  47497216ull     // 4096x2048 bf16
#define OFF_W1AT   64274432ull     // 1024x1024 bf16
#define OFF_W1BT   66371584ull     // 1024x1024 bf16
#define OFF_FBF    68468736ull     // 784x1024 bf16
#define OFF_XIN    70074368ull     // 960x1024 bf16
#define OFF_PF     72040448ull     // 784x1024 f32
#define OFF_XW     75251712ull     // 960x4096 f32
#define OFF_HBALL  90980352ull     // 1024x1024 bf16 (960 used)
#define OFF_HWBF   93077504ull     // 80x1024 bf16
#define OFF_ACAT   93241344ull     // 16x2048 bf16
#define OFF_H      93306880ull     // 16x1024 f32
#define OFF_C      93372416ull     // 16x1024 f32
#define OFF_CW     93437952ull     // 80x1024 f32
#define OFF_HPROJ  93765632ull     // 16x1024 f32
#define OFF_GS     93831168ull     // 16x4096 f32
#define OFF_GREC   94093312ull     // 80x4096 f32
#define WS_TOTAL   95404032ull
#define ZERO_BASE  OFF_ACAT
#define ZERO_BYTES (589824ull)     // Acat,h,c,cw,hproj contiguous

// ---------------- helpers ----------------
__device__ __forceinline__ unsigned short f2bf(float x){
  unsigned u = __float_as_uint(x);
  u += 0x7fffu + ((u >> 16) & 1u);
  return (unsigned short)(u >> 16);
}
__device__ __forceinline__ float sigm(float x){ return 1.f/(1.f+expf(-x)); }

// ---------------- converts ----------------
__global__ void k_cvt(const float* __restrict__ src, unsigned short* __restrict__ dst, int n){
  int idx = (blockIdx.x*256 + threadIdx.x)*4;
  if (idx >= n) return;
  f32x4 v = *(const f32x4*)(src + idx);
  us4 o; o[0]=f2bf(v[0]); o[1]=f2bf(v[1]); o[2]=f2bf(v[2]); o[3]=f2bf(v[3]);
  *(us4*)(dst + idx) = o;
}

// src rows x 1024 contiguous -> dst row stride dld with column offset doff
__global__ void k_cvt_str(const float* __restrict__ src, unsigned short* __restrict__ dst,
                          int n, int dld, int doff){
  int idx = (blockIdx.x*256 + threadIdx.x)*4;
  if (idx >= n) return;
  f32x4 v = *(const f32x4*)(src + idx);
  int r = idx >> 10, cc = idx & 1023;
  us4 o; o[0]=f2bf(v[0]); o[1]=f2bf(v[1]); o[2]=f2bf(v[2]); o[3]=f2bf(v[3]);
  *(us4*)(dst + (size_t)r*dld + doff + cc) = o;
}

// dst[c*dld + r] = bf16(src[(r0+r)*sld + c])
__global__ void k_transp(const float* __restrict__ src, int sld, int r0, int R, int Cc,
                         unsigned short* __restrict__ dst, int dld){
  __shared__ float t[32][33];
  int rb = blockIdx.x*32, cb = blockIdx.y*32;
  int tx = threadIdx.x & 31, ty = threadIdx.x >> 5;
  for (int i = ty; i < 32; i += 8){
    int r = rb + i, c = cb + tx;
    t[i][tx] = (r < R && c < Cc) ? src[(size_t)(r0 + r)*sld + c] : 0.f;
  }
  __syncthreads();
  for (int i = ty; i < 32; i += 8){
    int c = cb + i, r = rb + tx;
    if (c < Cc && r < R) dst[(size_t)c*dld + r] = f2bf(t[tx][i]);
  }
}

// gather word-LSTM inputs: row m=(w*80+s*16+b) -> emb[tok]
__global__ void k_gather(const float* __restrict__ emb, const int* __restrict__ reports,
                         unsigned short* __restrict__ Xin){
  int m = blockIdx.x;
  int w = m / 80, r = m % 80, s = r >> 4, b = r & 15;
  int tok = (w == 0) ? 1 : reports[b*60 + s*12 + (w-1)];
  const float* src = emb + ((size_t)tok << 10);
  int k = threadIdx.x * 4;
  f32x4 v = *(const f32x4*)(src + k);
  us4 o; o[0]=f2bf(v[0]); o[1]=f2bf(v[1]); o[2]=f2bf(v[2]); o[3]=f2bf(v[3]);
  *(us4*)(Xin + (size_t)m*1024 + k) = o;
}

// ---------------- generic bf16 MFMA GEMM ----------------
// A [M,K] bf16 row-major (lda); Bt [N,K] bf16 row-major (ldb); C f32.
// EPI: 0 plain, 1 +bias, 2 +bias & scatter rows to seq output
template<int BM,int BN,int BK,int WM,int WN,int EPI>
__global__ void k_gemm(const unsigned short* __restrict__ A, int lda,
                       const unsigned short* __restrict__ Bt, int ldb,
                       float* __restrict__ C, int ldc,
                       const float* __restrict__ bias,
                       int M, int N, int K)
{
  constexpr int LDT = BK + 8;
  __shared__ unsigned short As[BM*LDT];
  __shared__ unsigned short Bs[BN*LDT];
  const int tid  = threadIdx.x;
  const int lane = tid & 63;
  const int wave = tid >> 6;
  constexpr int WROWS = BM/WM, WCOLS = BN/WN;
  constexpr int FM = WROWS/16, FN = WCOLS/16;
  const int wm = wave / WN, wn = wave % WN;
  const int m0 = blockIdx.x * BM, n0 = blockIdx.y * BN;
  const int g = lane >> 4, fr = lane & 15;

  f32x4 acc[FM][FN];
  #pragma unroll
  for (int a=0;a<FM;a++)
    #pragma unroll
    for (int b=0;b<FN;b++) acc[a][b] = (f32x4){0.f,0.f,0.f,0.f};

  for (int k0 = 0; k0 < K; k0 += BK) {
    if (k0) __syncthreads();
    for (int i = tid; i < BM*BK/8; i += 256) {
      int r = i / (BK/8), cc = (i % (BK/8)) * 8;
      int gr = m0 + r; gr = gr < M ? gr : M-1;
      u32x4 v = *(const u32x4*)(A + (size_t)gr*lda + (k0 + cc));
      *(u32x4*)(As + r*LDT + cc) = v;
    }
    for (int i = tid; i < BN*BK/8; i += 256) {
      int r = i / (BK/8), cc = (i % (BK/8)) * 8;
      int gr = n0 + r; gr = gr < N ? gr : N-1;
      u32x4 v = *(const u32x4*)(Bt + (size_t)gr*ldb + (k0 + cc));
      *(u32x4*)(Bs + r*LDT + cc) = v;
    }
    __syncthreads();
    #pragma unroll
    for (int kk = 0; kk < BK; kk += 32) {
      short8 af[FM], bt[FN];
      #pragma unroll
      for (int fm=0; fm<FM; fm++)
        af[fm] = *(const short8*)(As + (wm*WROWS + fm*16 + fr)*LDT + kk + g*8);
      #pragma unroll
      for (int fn=0; fn<FN; fn++)
        bt[fn] = *(const short8*)(Bs + (wn*WCOLS + fn*16 + fr)*LDT + kk + g*8);
      #pragma unroll
      for (int fm=0; fm<FM; fm++)
        #pragma unroll
        for (int fn=0; fn<FN; fn++)
          acc[fm][fn] = __builtin_amdgcn_mfma_f32_16x16x32_bf16(af[fm], bt[fn], acc[fm][fn], 0, 0, 0);
    }
  }

  #pragma unroll
  for (int fm=0; fm<FM; fm++)
    #pragma unroll
    for (int fn=0; fn<FN; fn++)
      #pragma unroll
      for (int j=0; j<4; j++){
        int m = m0 + wm*WROWS + fm*16 + g*4 + j;
        int n = n0 + wn*WCOLS + fn*16 + fr;
        if (m < M && n < N) {
          float v = acc[fm][fn][j];
          if (EPI >= 1) v += bias[n];
          if (EPI == 2) {
            int b = m & 15, s = (m >> 4) % 5, w = m / 80;
            C[(size_t)((b*5 + s)*12 + w)*V_ + n] = v;
          } else {
            C[(size_t)m*ldc + n] = v;
          }
        }
      }
}

// ---------------- LSTM pointwise ----------------
__global__ void k_cell_s(const float* __restrict__ Gs, const float* __restrict__ bih,
                         const float* __restrict__ bhh, float* __restrict__ h,
                         float* __restrict__ c, unsigned short* __restrict__ Acat,
                         unsigned short* __restrict__ HWbf, int s)
{
  int idx = blockIdx.x*256 + threadIdx.x;   // 16*1024
  int b = idx >> 10, j = idx & 1023;
  const float* gr = Gs + b*4096;
  float gi = gr[j]        + bih[j]        + bhh[j];
  float gf = gr[1024 + j] + bih[1024 + j] + bhh[1024 + j];
  float gg = gr[2048 + j] + bih[2048 + j] + bhh[2048 + j];
  float go = gr[3072 + j] + bih[3072 + j] + bhh[3072 + j];
  float cn = sigm(gf)*c[idx] + sigm(gi)*tanhf(gg);
  float hn = sigm(go)*tanhf(cn);
  c[idx] = cn; h[idx] = hn;
  unsigned short hb = f2bf(hn);
  Acat[b*2048 + 1024 + j] = hb;
  HWbf[(s*16 + b)*1024 + j] = hb;
}

__global__ void k_cell_w(const float* __restrict__ Grec, const float* __restrict__ Xw,
                         const float* __restrict__ bih, const float* __restrict__ bhh,
                         float* __restrict__ cw, unsigned short* __restrict__ HWbf,
                         unsigned short* __restrict__ Hball)
{
  int idx = blockIdx.x*256 + threadIdx.x;   // 80*1024
  int r = idx >> 10, j = idx & 1023;
  const float* g1 = Grec + r*4096;
  const float* g2 = Xw   + r*4096;
  float gi = g1[j]        + g2[j]        + bih[j]        + bhh[j];
  float gf = g1[1024 + j] + g2[1024 + j] + bih[1024 + j] + bhh[1024 + j];
  float gg = g1[2048 + j] + g2[2048 + j] + bih[2048 + j] + bhh[2048 + j];
  float go = g1[3072 + j] + g2[3072 + j] + bih[3072 + j] + bhh[3072 + j];
  float cn = sigm(gf)*cw[idx] + sigm(gi)*tanhf(gg);
  float hn = sigm(go)*tanhf(cn);
  cw[idx] = cn;
  unsigned short hb = f2bf(hn);
  HWbf[idx] = hb;
  Hball[idx] = hb;
}

// ---------------- attention (one block per batch row) ----------------
template<int INIT>
__global__ void k_attn(const float* __restrict__ PF, const float* __restrict__ hproj,
                       const float* __restrict__ features, const float* __restrict__ w2,
                       const float* __restrict__ h, const float* __restrict__ stop_w,
                       const float* __restrict__ stop_b,
                       unsigned short* __restrict__ Acat, float* __restrict__ outp, int s)
{
  const int b = blockIdx.x, tid = threadIdx.x;
  __shared__ float hp[H_];
  __shared__ float red[4];
  __shared__ float evals[NL_];
  __shared__ float scs[NL_];
  for (int k = tid; k < H_; k += 256) hp[k] = hproj[b*H_ + k];
  __syncthreads();
  for (int n = 0; n < NL_; n++){
    float p = 0.f;
    const float* pf = PF + ((size_t)(b*NL_ + n))*H_;
    for (int k = tid; k < H_; k += 256) p += tanhf(pf[k] + hp[k]) * w2[k];
    #pragma unroll
    for (int o = 32; o; o >>= 1) p += __shfl_down(p, o, 64);
    if ((tid & 63) == 0) red[tid >> 6] = p;
    __syncthreads();
    if (tid == 0) evals[n] = red[0] + red[1] + red[2] + red[3];
    __syncthreads();
  }
  float mx = -1e30f;
  for (int n = 0; n < NL_; n++) mx = fmaxf(mx, evals[n]);
  float dn = 0.f;
  for (int n = 0; n < NL_; n++) dn += expf(evals[n] - mx);
  if (tid < NL_) {
    float sc = expf(evals[tid] - mx) / dn;
    scs[tid] = sc;
    if (!INIT) outp[OUT_SCORE + (b*5 + s)*NL_ + tid] = sc;
  }
  __syncthreads();
  for (int f = tid; f < H_; f += 256){
    float a = 0.f;
    #pragma unroll 7
    for (int n = 0; n < NL_; n++) a += scs[n] * features[((size_t)(b*NL_ + n))*H_ + f];
    Acat[b*2048 + f] = f2bf(a);
  }
  if (!INIT) {
    float p = 0.f;
    for (int k = tid; k < H_; k += 256) p += h[b*H_ + k] * stop_w[k];
    #pragma unroll
    for (int o = 32; o; o >>= 1) p += __shfl_down(p, o, 64);
    if ((tid & 63) == 0) red[tid >> 6] = p;
    __syncthreads();
    if (tid == 0) outp[OUT_STOP + b*5 + s] = sigm(red[0]+red[1]+red[2]+red[3] + stop_b[0]);
  }
}

// ---------------- host ----------------
extern "C" void kernel_launch(void* const* d_in, const int* in_sizes, int n_in,
                              void* d_out, int out_size, void* d_ws, size_t ws_size,
                              hipStream_t stream)
{
  const float* features = (const float*)d_in[0];
  const int*   reports  = (const int*)d_in[1];
  const float* attn_w1  = (const float*)d_in[2];
  const float* attn_b1  = (const float*)d_in[3];
  const float* attn_w2  = (const float*)d_in[4];
  const float* s_wih    = (const float*)d_in[6];
  const float* s_whh    = (const float*)d_in[7];
  const float* s_bih    = (const float*)d_in[8];
  const float* s_bhh    = (const float*)d_in[9];
  const float* stop_w   = (const float*)d_in[10];
  const float* stop_b   = (const float*)d_in[11];
  const float* emb      = (const float*)d_in[12];
  const float* w_wih    = (const float*)d_in[13];
  const float* w_whh    = (const float*)d_in[14];
  const float* w_bih    = (const float*)d_in[15];
  const float* w_bhh    = (const float*)d_in[16];
  const float* fc_w     = (const float*)d_in[17];
  const float* fc_b     = (const float*)d_in[18];
  float* out = (float*)d_out;
  char*  ws  = (char*)d_ws;
  if (ws_size < WS_TOTAL) return;   // insufficient scratch: fail visibly

  unsigned short* FCWT  = (unsigned short*)(ws + OFF_FCWT);
  unsigned short* WWHH  = (unsigned short*)(ws + OFF_WWHH);
  unsigned short* WWIH  = (unsigned short*)(ws + OFF_WWIH);
  unsigned short* WSCAT = (unsigned short*)(ws + OFF_WSCAT);
  unsigned short* W1AT  = (unsigned short*)(ws + OFF_W1AT);
  unsigned short* W1BT  = (unsigned short*)(ws + OFF_W1BT);
  unsigned short* FBF   = (unsigned short*)(ws + OFF_FBF);
  unsigned short* XIN   = (unsigned short*)(ws + OFF_XIN);
  float*          PF    = (float*)(ws + OFF_PF);
  float*          XW    = (float*)(ws + OFF_XW);
  unsigned short* HBALL = (unsigned short*)(ws + OFF_HBALL);
  unsigned short* HWBF  = (unsigned short*)(ws + OFF_HWBF);
  unsigned short* ACAT  = (unsigned short*)(ws + OFF_ACAT);
  float*          Hst   = (float*)(ws + OFF_H);
  float*          Cst   = (float*)(ws + OFF_C);
  float*          CW    = (float*)(ws + OFF_CW);
  float*          HPROJ = (float*)(ws + OFF_HPROJ);
  float*          GS    = (float*)(ws + OFF_GS);
  float*          GREC  = (float*)(ws + OFF_GREC);

  hipMemsetAsync(ws + ZERO_BASE, 0, ZERO_BYTES, stream);

  // conversions / transposes
  k_cvt<<<784, 256, 0, stream>>>(features, FBF, 802816);
  k_cvt<<<4096, 256, 0, stream>>>(w_whh, WWHH, 4194304);
  k_cvt<<<4096, 256, 0, stream>>>(w_wih, WWIH, 4194304);
  k_cvt_str<<<4096, 256, 0, stream>>>(s_wih, WSCAT, 4194304, 2048, 0);
  k_cvt_str<<<4096, 256, 0, stream>>>(s_whh, WSCAT, 4194304, 2048, 1024);
  k_transp<<<dim3(32,32),  256, 0, stream>>>(attn_w1, 1024, 0,    1024, 1024,  W1AT, 1024);
  k_transp<<<dim3(32,32),  256, 0, stream>>>(attn_w1, 1024, 1024, 1024, 1024,  W1BT, 1024);
  k_transp<<<dim3(32,469), 256, 0, stream>>>(fc_w,   15000, 0,    1024, 15000, FCWT, 1024);
  k_gather<<<960, 256, 0, stream>>>(emb, reports, XIN);

  // PF = features @ w1[:F] + b1   (M=784,N=1024,K=1024)
  k_gemm<16,128,64,1,4,1><<<dim3(49,8), 256, 0, stream>>>(FBF,1024, W1AT,1024, PF,1024, attn_b1, 784,1024,1024);
  // Xw = Xin @ w_wih^T            (M=960,N=4096,K=1024)
  k_gemm<64,128,64,2,2,0><<<dim3(15,32), 256, 0, stream>>>(XIN,1024, WWIH,1024, XW,4096, nullptr, 960,4096,1024);

  // att0 (h=0: hproj zeroed)
  k_attn<1><<<16, 256, 0, stream>>>(PF, HPROJ, features, attn_w2, Hst, stop_w, stop_b, ACAT, out, 0);

  // sentence chain
  for (int s = 0; s < S_; s++){
    k_gemm<16,128,64,1,4,0><<<dim3(1,32), 256, 0, stream>>>(ACAT,2048, WSCAT,2048, GS,4096, nullptr, 16,4096,2048);
    k_cell_s<<<64, 256, 0, stream>>>(GS, s_bih, s_bhh, Hst, Cst, ACAT, HWBF, s);
    k_gemm<16,128,64,1,4,0><<<dim3(1,8), 256, 0, stream>>>(ACAT + 1024, 2048, W1BT,1024, HPROJ,1024, nullptr, 16,1024,1024);
    k_attn<0><<<16, 256, 0, stream>>>(PF, HPROJ, features, attn_w2, Hst, stop_w, stop_b, ACAT, out, s);
  }

  // word chain (batched across the 5 sentences)
  for (int w = 0; w < W_; w++){
    k_gemm<16,128,64,1,4,0><<<dim3(5,32), 256, 0, stream>>>(HWBF,1024, WWHH,1024, GREC,4096, nullptr, 80,4096,1024);
    k_cell_w<<<320, 256, 0, stream>>>(GREC, XW + (size_t)w*80*4096, w_bih, w_bhh, CW, HWBF,
                                      HBALL + (size_t)w*80*1024);
  }

  // fc: preds = Hball @ fc_w + fc_b, scattered into seq layout
  k_gemm<128,128,64,2,2,2><<<dim3(8,118), 256, 0, stream>>>(HBALL,1024, FCWT,1024, out,V_, fc_b, 960,15000,1024);
}

// Round 2
// 770.438 us; speedup vs baseline: 2.0519x; 2.0519x over previous
//
#include <hip/hip_runtime.h>
#include <hip/hip_bf16.h>

// ---------------- problem constants ----------------
#define B_  16
#define S_  5
#define W_  12
#define NL_ 49
#define H_  1024
#define V_  15000
#define SEQ_N   14400000          // B*S*W*V
#define STOP_N  80
#define OUT_STOP (SEQ_N)
#define OUT_SCORE (SEQ_N + STOP_N)

typedef __attribute__((ext_vector_type(8))) short     short8;
typedef __attribute__((ext_vector_type(4))) float     f32x4;
typedef __attribute__((ext_vector_type(4))) unsigned int u32x4;
typedef __attribute__((ext_vector_type(4))) unsigned short us4;

// ---------------- ws layout (bytes) ----------------
#define OFF_FCWT   0ull            // 15000x1024 bf16  30,720,000
#define OFF_WWHH   30720000ull     // 4096x1024 bf16
#define OFF_WWIH   39108608ull     // 4096x1024 bf16
#define OFF_WSCAT  47497216ull     // 4096x2048 bf16
#define OFF_W1AT   64274432ull     // 1024x1024 bf16
#define OFF_W1BT   66371584ull     // 1024x1024 bf16
#define OFF_FBF    68468736ull     // 784x1024 bf16
#define OFF_XIN    70074368ull     // 960x1024 bf16
#define OFF_PF     72040448ull     // 784x1024 f32
#define OFF_XW     75251712ull     // 960x4096 f32
#define OFF_HBALL  90980352ull     // 1024x1024 bf16 (960 used)
#define OFF_HWBF   93077504ull     // 80x1024 bf16
#define OFF_ACAT   93241344ull     // 16x2048 bf16
#define OFF_H      93306880ull     // 16x1024 f32
#define OFF_C      93372416ull     // 16x1024 f32
#define OFF_CW     93437952ull     // 80x1024 f32
#define OFF_HPROJ  93765632ull     // 16x1024 f32
#define OFF_GS     93831168ull     // 16x4096 f32
#define OFF_GREC   94093312ull     // 80x4096 f32
#define OFF_EVAL   95404032ull     // 784 f32
#define WS_TOTAL   95407168ull
#define ZERO_BASE  OFF_ACAT
#define ZERO_BYTES (589824ull)     // Acat,h,c,cw,hproj contiguous

// ---------------- helpers ----------------
__device__ __forceinline__ unsigned short f2bf(float x){
  unsigned u = __float_as_uint(x);
  u += 0x7fffu + ((u >> 16) & 1u);
  return (unsigned short)(u >> 16);
}
__device__ __forceinline__ float sigm(float x){ return 1.f/(1.f+expf(-x)); }

// ---------------- converts ----------------
__global__ void k_cvt(const float* __restrict__ src, unsigned short* __restrict__ dst, int n){
  int idx = (blockIdx.x*256 + threadIdx.x)*4;
  if (idx >= n) return;
  f32x4 v = *(const f32x4*)(src + idx);
  us4 o; o[0]=f2bf(v[0]); o[1]=f2bf(v[1]); o[2]=f2bf(v[2]); o[3]=f2bf(v[3]);
  *(us4*)(dst + idx) = o;
}

// src rows x 1024 contiguous -> dst row stride dld with column offset doff
__global__ void k_cvt_str(const float* __restrict__ src, unsigned short* __restrict__ dst,
                          int n, int dld, int doff){
  int idx = (blockIdx.x*256 + threadIdx.x)*4;
  if (idx >= n) return;
  f32x4 v = *(const f32x4*)(src + idx);
  int r = idx >> 10, cc = idx & 1023;
  us4 o; o[0]=f2bf(v[0]); o[1]=f2bf(v[1]); o[2]=f2bf(v[2]); o[3]=f2bf(v[3]);
  *(us4*)(dst + (size_t)r*dld + doff + cc) = o;
}

// dst[c*dld + r] = bf16(src[(r0+r)*sld + c])
__global__ void k_transp(const float* __restrict__ src, int sld, int r0, int R, int Cc,
                         unsigned short* __restrict__ dst, int dld){
  __shared__ float t[32][33];
  int rb = blockIdx.x*32, cb = blockIdx.y*32;
  int tx = threadIdx.x & 31, ty = threadIdx.x >> 5;
  for (int i = ty; i < 32; i += 8){
    int r = rb + i, c = cb + tx;
    t[i][tx] = (r < R && c < Cc) ? src[(size_t)(r0 + r)*sld + c] : 0.f;
  }
  __syncthreads();
  for (int i = ty; i < 32; i += 8){
    int c = cb + i, r = rb + tx;
    if (c < Cc && r < R) dst[(size_t)c*dld + r] = f2bf(t[tx][i]);
  }
}

// gather word-LSTM inputs: row m=(w*80+s*16+b) -> emb[tok]
__global__ void k_gather(const float* __restrict__ emb, const int* __restrict__ reports,
                         unsigned short* __restrict__ Xin){
  int m = blockIdx.x;
  int w = m / 80, r = m % 80, s = r >> 4, b = r & 15;
  int tok = (w == 0) ? 1 : reports[b*60 + s*12 + (w-1)];
  const float* src = emb + ((size_t)tok << 10);
  int k = threadIdx.x * 4;
  f32x4 v = *(const f32x4*)(src + k);
  us4 o; o[0]=f2bf(v[0]); o[1]=f2bf(v[1]); o[2]=f2bf(v[2]); o[3]=f2bf(v[3]);
  *(us4*)(Xin + (size_t)m*1024 + k) = o;
}

// ---------------- generic bf16 MFMA GEMM ----------------
// A [M,K] bf16 row-major (lda); Bt [N,K] bf16 row-major (ldb); C f32.
// EPI: 0 plain, 1 +bias, 2 +bias & scatter rows to seq output
template<int BM,int BN,int BK,int WM,int WN,int EPI>
__global__ void k_gemm(const unsigned short* __restrict__ A, int lda,
                       const unsigned short* __restrict__ Bt, int ldb,
                       float* __restrict__ C, int ldc,
                       const float* __restrict__ bias,
                       int M, int N, int K)
{
  constexpr int LDT = BK + 8;
  __shared__ unsigned short As[BM*LDT];
  __shared__ unsigned short Bs[BN*LDT];
  const int tid  = threadIdx.x;
  const int lane = tid & 63;
  const int wave = tid >> 6;
  constexpr int WROWS = BM/WM, WCOLS = BN/WN;
  constexpr int FM = WROWS/16, FN = WCOLS/16;
  const int wm = wave / WN, wn = wave % WN;
  const int m0 = blockIdx.x * BM, n0 = blockIdx.y * BN;
  const int g = lane >> 4, fr = lane & 15;

  f32x4 acc[FM][FN];
  #pragma unroll
  for (int a=0;a<FM;a++)
    #pragma unroll
    for (int b=0;b<FN;b++) acc[a][b] = (f32x4){0.f,0.f,0.f,0.f};

  for (int k0 = 0; k0 < K; k0 += BK) {
    if (k0) __syncthreads();
    for (int i = tid; i < BM*BK/8; i += 256) {
      int r = i / (BK/8), cc = (i % (BK/8)) * 8;
      int gr = m0 + r; gr = gr < M ? gr : M-1;
      u32x4 v = *(const u32x4*)(A + (size_t)gr*lda + (k0 + cc));
      *(u32x4*)(As + r*LDT + cc) = v;
    }
    for (int i = tid; i < BN*BK/8; i += 256) {
      int r = i / (BK/8), cc = (i % (BK/8)) * 8;
      int gr = n0 + r; gr = gr < N ? gr : N-1;
      u32x4 v = *(const u32x4*)(Bt + (size_t)gr*ldb + (k0 + cc));
      *(u32x4*)(Bs + r*LDT + cc) = v;
    }
    __syncthreads();
    #pragma unroll
    for (int kk = 0; kk < BK; kk += 32) {
      short8 af[FM], bt[FN];
      #pragma unroll
      for (int fm=0; fm<FM; fm++)
        af[fm] = *(const short8*)(As + (wm*WROWS + fm*16 + fr)*LDT + kk + g*8);
      #pragma unroll
      for (int fn=0; fn<FN; fn++)
        bt[fn] = *(const short8*)(Bs + (wn*WCOLS + fn*16 + fr)*LDT + kk + g*8);
      #pragma unroll
      for (int fm=0; fm<FM; fm++)
        #pragma unroll
        for (int fn=0; fn<FN; fn++)
          acc[fm][fn] = __builtin_amdgcn_mfma_f32_16x16x32_bf16(af[fm], bt[fn], acc[fm][fn], 0, 0, 0);
    }
  }

  #pragma unroll
  for (int fm=0; fm<FM; fm++)
    #pragma unroll
    for (int fn=0; fn<FN; fn++)
      #pragma unroll
      for (int j=0; j<4; j++){
        int m = m0 + wm*WROWS + fm*16 + g*4 + j;
        int n = n0 + wn*WCOLS + fn*16 + fr;
        if (m < M && n < N) {
          float v = acc[fm][fn][j];
          if (EPI >= 1) v += bias[n];
          if (EPI == 2) {
            int b = m & 15, s = (m >> 4) % 5, w = m / 80;
            C[(size_t)((b*5 + s)*12 + w)*V_ + n] = v;
          } else {
            C[(size_t)m*ldc + n] = v;
          }
        }
      }
}

// ---------------- LSTM pointwise ----------------
__global__ void k_cell_s(const float* __restrict__ Gs, const float* __restrict__ bih,
                         const float* __restrict__ bhh, float* __restrict__ h,
                         float* __restrict__ c, unsigned short* __restrict__ Acat,
                         unsigned short* __restrict__ HWbf, int s)
{
  int idx = blockIdx.x*256 + threadIdx.x;   // 16*1024
  int b = idx >> 10, j = idx & 1023;
  const float* gr = Gs + b*4096;
  float gi = gr[j]        + bih[j]        + bhh[j];
  float gf = gr[1024 + j] + bih[1024 + j] + bhh[1024 + j];
  float gg = gr[2048 + j] + bih[2048 + j] + bhh[2048 + j];
  float go = gr[3072 + j] + bih[3072 + j] + bhh[3072 + j];
  float cn = sigm(gf)*c[idx] + sigm(gi)*tanhf(gg);
  float hn = sigm(go)*tanhf(cn);
  c[idx] = cn; h[idx] = hn;
  unsigned short hb = f2bf(hn);
  Acat[b*2048 + 1024 + j] = hb;
  HWbf[(s*16 + b)*1024 + j] = hb;
}

__global__ void k_cell_w(const float* __restrict__ Grec, const float* __restrict__ Xw,
                         const float* __restrict__ bih, const float* __restrict__ bhh,
                         float* __restrict__ cw, unsigned short* __restrict__ HWbf,
                         unsigned short* __restrict__ Hball)
{
  int idx = blockIdx.x*256 + threadIdx.x;   // 80*1024
  int r = idx >> 10, j = idx & 1023;
  const float* g1 = Grec + r*4096;
  const float* g2 = Xw   + r*4096;
  float gi = g1[j]        + g2[j]        + bih[j]        + bhh[j];
  float gf = g1[1024 + j] + g2[1024 + j] + bih[1024 + j] + bhh[1024 + j];
  float gg = g1[2048 + j] + g2[2048 + j] + bih[2048 + j] + bhh[2048 + j];
  float go = g1[3072 + j] + g2[3072 + j] + bih[3072 + j] + bhh[3072 + j];
  float cn = sigm(gf)*cw[idx] + sigm(gi)*tanhf(gg);
  float hn = sigm(go)*tanhf(cn);
  cw[idx] = cn;
  unsigned short hb = f2bf(hn);
  HWbf[idx] = hb;
  Hball[idx] = hb;
}

// ---------------- attention, parallelized ----------------
// evals[b*49+n] = sum_k tanh(PF[b,n,k] + hproj[b,k]) * w2[k]; 784 blocks
__global__ void k_attn_e(const float* __restrict__ PF, const float* __restrict__ hproj,
                         const float* __restrict__ w2, float* __restrict__ evals)
{
  const int bn = blockIdx.x;            // 0..783
  const int b  = bn / NL_;
  const int tid = threadIdx.x;
  __shared__ float red[4];
  const float* pf = PF + ((size_t)bn << 10);
  const float* hp = hproj + (b << 10);
  int k = tid * 4;
  f32x4 a = *(const f32x4*)(pf + k);
  f32x4 hh = *(const f32x4*)(hp + k);
  f32x4 w = *(const f32x4*)(w2 + k);
  float p = tanhf(a[0]+hh[0])*w[0] + tanhf(a[1]+hh[1])*w[1]
          + tanhf(a[2]+hh[2])*w[2] + tanhf(a[3]+hh[3])*w[3];
  #pragma unroll
  for (int o = 32; o; o >>= 1) p += __shfl_down(p, o, 64);
  if ((tid & 63) == 0) red[tid >> 6] = p;
  __syncthreads();
  if (tid == 0) evals[bn] = red[0] + red[1] + red[2] + red[3];
}

// softmax over 49, weighted feature sum, optional scores/stop outputs; 16 blocks
template<int INIT>
__global__ void k_attn_fin(const float* __restrict__ evals, const float* __restrict__ features,
                           const float* __restrict__ h, const float* __restrict__ stop_w,
                           const float* __restrict__ stop_b,
                           unsigned short* __restrict__ Acat, float* __restrict__ outp, int s)
{
  const int b = blockIdx.x, tid = threadIdx.x;
  __shared__ float scs[64];
  __shared__ float red[4];
  if (tid < 64){
    float e = (tid < NL_) ? evals[b*NL_ + tid] : -1e30f;
    float mx = e;
    #pragma unroll
    for (int o = 32; o; o >>= 1) mx = fmaxf(mx, __shfl_xor(mx, o, 64));
    float ex = (tid < NL_) ? expf(e - mx) : 0.f;
    float dn = ex;
    #pragma unroll
    for (int o = 32; o; o >>= 1) dn += __shfl_xor(dn, o, 64);
    float sc = ex / dn;
    if (tid < NL_){
      scs[tid] = sc;
      if (!INIT) outp[OUT_SCORE + (b*5 + s)*NL_ + tid] = sc;
    }
  }
  __syncthreads();
  // att[b, f0..f0+3] = sum_n scs[n] * features[b,n,f]
  {
    int f0 = tid * 4;
    f32x4 a = (f32x4){0.f,0.f,0.f,0.f};
    const float* fb = features + (((size_t)b*NL_) << 10) + f0;
    #pragma unroll 7
    for (int n = 0; n < NL_; n++){
      f32x4 v = *(const f32x4*)(fb + ((size_t)n << 10));
      float sc = scs[n];
      a[0] += sc*v[0]; a[1] += sc*v[1]; a[2] += sc*v[2]; a[3] += sc*v[3];
    }
    us4 o4; o4[0]=f2bf(a[0]); o4[1]=f2bf(a[1]); o4[2]=f2bf(a[2]); o4[3]=f2bf(a[3]);
    *(us4*)(Acat + b*2048 + f0) = o4;
  }
  if (!INIT){
    int k = tid * 4;
    f32x4 hv = *(const f32x4*)(h + (b << 10) + k);
    f32x4 sw = *(const f32x4*)(stop_w + k);
    float p = hv[0]*sw[0] + hv[1]*sw[1] + hv[2]*sw[2] + hv[3]*sw[3];
    #pragma unroll
    for (int o = 32; o; o >>= 1) p += __shfl_down(p, o, 64);
    if ((tid & 63) == 0) red[tid >> 6] = p;
    __syncthreads();
    if (tid == 0) outp[OUT_STOP + b*5 + s] = sigm(red[0]+red[1]+red[2]+red[3] + stop_b[0]);
  }
}

// ---------------- host ----------------
extern "C" void kernel_launch(void* const* d_in, const int* in_sizes, int n_in,
                              void* d_out, int out_size, void* d_ws, size_t ws_size,
                              hipStream_t stream)
{
  const float* features = (const float*)d_in[0];
  const int*   reports  = (const int*)d_in[1];
  const float* attn_w1  = (const float*)d_in[2];
  const float* attn_b1  = (const float*)d_in[3];
  const float* attn_w2  = (const float*)d_in[4];
  const float* s_wih    = (const float*)d_in[6];
  const float* s_whh    = (const float*)d_in[7];
  const float* s_bih    = (const float*)d_in[8];
  const float* s_bhh    = (const float*)d_in[9];
  const float* stop_w   = (const float*)d_in[10];
  const float* stop_b   = (const float*)d_in[11];
  const float* emb      = (const float*)d_in[12];
  const float* w_wih    = (const float*)d_in[13];
  const float* w_whh    = (const float*)d_in[14];
  const float* w_bih    = (const float*)d_in[15];
  const float* w_bhh    = (const float*)d_in[16];
  const float* fc_w     = (const float*)d_in[17];
  const float* fc_b     = (const float*)d_in[18];
  float* out = (float*)d_out;
  char*  ws  = (char*)d_ws;
  if (ws_size < WS_TOTAL) return;   // insufficient scratch: fail visibly

  unsigned short* FCWT  = (unsigned short*)(ws + OFF_FCWT);
  unsigned short* WWHH  = (unsigned short*)(ws + OFF_WWHH);
  unsigned short* WWIH  = (unsigned short*)(ws + OFF_WWIH);
  unsigned short* WSCAT = (unsigned short*)(ws + OFF_WSCAT);
  unsigned short* W1AT  = (unsigned short*)(ws + OFF_W1AT);
  unsigned short* W1BT  = (unsigned short*)(ws + OFF_W1BT);
  unsigned short* FBF   = (unsigned short*)(ws + OFF_FBF);
  unsigned short* XIN   = (unsigned short*)(ws + OFF_XIN);
  float*          PF    = (float*)(ws + OFF_PF);
  float*          XW    = (float*)(ws + OFF_XW);
  unsigned short* HBALL = (unsigned short*)(ws + OFF_HBALL);
  unsigned short* HWBF  = (unsigned short*)(ws + OFF_HWBF);
  unsigned short* ACAT  = (unsigned short*)(ws + OFF_ACAT);
  float*          Hst   = (float*)(ws + OFF_H);
  float*          Cst   = (float*)(ws + OFF_C);
  float*          CW    = (float*)(ws + OFF_CW);
  float*          HPROJ = (float*)(ws + OFF_HPROJ);
  float*          GS    = (float*)(ws + OFF_GS);
  float*          GREC  = (float*)(ws + OFF_GREC);
  float*          EVAL  = (float*)(ws + OFF_EVAL);

  hipMemsetAsync(ws + ZERO_BASE, 0, ZERO_BYTES, stream);

  // conversions / transposes
  k_cvt<<<784, 256, 0, stream>>>(features, FBF, 802816);
  k_cvt<<<4096, 256, 0, stream>>>(w_whh, WWHH, 4194304);
  k_cvt<<<4096, 256, 0, stream>>>(w_wih, WWIH, 4194304);
  k_cvt_str<<<4096, 256, 0, stream>>>(s_wih, WSCAT, 4194304, 2048, 0);
  k_cvt_str<<<4096, 256, 0, stream>>>(s_whh, WSCAT, 4194304, 2048, 1024);
  k_transp<<<dim3(32,32),  256, 0, stream>>>(attn_w1, 1024, 0,    1024, 1024,  W1AT, 1024);
  k_transp<<<dim3(32,32),  256, 0, stream>>>(attn_w1, 1024, 1024, 1024, 1024,  W1BT, 1024);
  k_transp<<<dim3(32,469), 256, 0, stream>>>(fc_w,   15000, 0,    1024, 15000, FCWT, 1024);
  k_gather<<<960, 256, 0, stream>>>(emb, reports, XIN);

  // PF = features @ w1[:F] + b1   (M=784,N=1024,K=1024)
  k_gemm<64,64,256,2,2,1><<<dim3(13,16), 256, 0, stream>>>(FBF,1024, W1AT,1024, PF,1024, attn_b1, 784,1024,1024);
  // Xw = Xin @ w_wih^T            (M=960,N=4096,K=1024)
  k_gemm<64,128,128,2,2,0><<<dim3(15,32), 256, 0, stream>>>(XIN,1024, WWIH,1024, XW,4096, nullptr, 960,4096,1024);

  // att0 (h=0: hproj zeroed)
  k_attn_e<<<784, 256, 0, stream>>>(PF, HPROJ, attn_w2, EVAL);
  k_attn_fin<1><<<16, 256, 0, stream>>>(EVAL, features, Hst, stop_w, stop_b, ACAT, out, 0);

  // sentence chain
  for (int s = 0; s < S_; s++){
    k_gemm<16,64,256,1,4,0><<<dim3(1,64), 256, 0, stream>>>(ACAT,2048, WSCAT,2048, GS,4096, nullptr, 16,4096,2048);
    k_cell_s<<<64, 256, 0, stream>>>(GS, s_bih, s_bhh, Hst, Cst, ACAT, HWBF, s);
    k_gemm<16,64,256,1,4,0><<<dim3(1,16), 256, 0, stream>>>(ACAT + 1024, 2048, W1BT,1024, HPROJ,1024, nullptr, 16,1024,1024);
    k_attn_e<<<784, 256, 0, stream>>>(PF, HPROJ, attn_w2, EVAL);
    k_attn_fin<0><<<16, 256, 0, stream>>>(EVAL, features, Hst, stop_w, stop_b, ACAT, out, s);
  }

  // word chain (batched across the 5 sentences)
  for (int w = 0; w < W_; w++){
    k_gemm<16,64,256,1,4,0><<<dim3(5,64), 256, 0, stream>>>(HWBF,1024, WWHH,1024, GREC,4096, nullptr, 80,4096,1024);
    k_cell_w<<<320, 256, 0, stream>>>(GREC, XW + (size_t)w*80*4096, w_bih, w_bhh, CW, HWBF,
                                      HBALL + (size_t)w*80*1024);
  }

  // fc: preds = Hball @ fc_w + fc_b, scattered into seq layout
  k_gemm<128,128,128,2,2,2><<<dim3(8,118), 256, 0, stream>>>(HBALL,1024, FCWT,1024, out,V_, fc_b, 960,15000,1024);
}